// Round 3
// baseline (508.191 us; speedup 1.0000x reference)
//
#include <hip/hip_runtime.h>

#define HW     4096
#define CKD    64
#define CVD    512
#define NBATCH 8
#define BQ     64
#define NIT    64      // HW / 64 m-tiles
#define PSTR   72      // P rows: 72 shorts = 144 B (multiple of 16)

typedef __attribute__((ext_vector_type(8))) short  short8;
typedef __attribute__((ext_vector_type(4))) float  floatx4;
typedef __attribute__((ext_vector_type(4))) int    intx4;
typedef __attribute__((ext_vector_type(2))) int    intx2;

static __device__ __forceinline__ unsigned short f2bf(float f) {
  unsigned u = __float_as_uint(f);
  u = (u + 0x7fffu + ((u >> 16) & 1u)) >> 16;   // RTNE
  return (unsigned short)u;
}
static __device__ __forceinline__ unsigned pack2(float a, float b) {
  return (unsigned)f2bf(a) | ((unsigned)f2bf(b) << 16);
}
static __device__ __forceinline__ short8 ld_bf16x8(const unsigned short* p) {
  union { intx4 i; short8 s; } u;
  u.i = *(const intx4*)p;
  return u.s;
}
static __device__ __forceinline__ short8 cvt_f32x8(const float* p) {
  short8 f;
  #pragma unroll
  for (int j = 0; j < 8; ++j) f[j] = (short)f2bf(p[j]);
  return f;
}
static __device__ __forceinline__ short8 cvt_f32x8_strided(const float* p) {
  short8 f;
  #pragma unroll
  for (int j = 0; j < 8; ++j) f[j] = (short)f2bf(p[(size_t)j * HW]);
  return f;
}

// ---- fused prep: Mk/Qk f32 [b][c][m] -> bf16 [b][m][c] (transpose),
// ----             Mv f32 [b][cv][m]  -> bf16 same layout
__global__ __launch_bounds__(256) void prep(
    const float* __restrict__ Mk, const float* __restrict__ Qk,
    const float* __restrict__ Mv,
    unsigned short* __restrict__ mkT, unsigned short* __restrict__ qkT,
    unsigned short* __restrict__ mvB)
{
  const int bid = blockIdx.x, t = threadIdx.x;
  if (bid < 1024) {
    // transpose one 64c x 64m tile
    __shared__ alignas(16) short tile[64 * PSTR];
    const float* src = (bid >> 9) ? Qk : Mk;
    unsigned short* dst = (bid >> 9) ? qkT : mkT;
    const int b  = (bid >> 6) & 7;
    const int m0 = (bid & 63) * 64;
    src += (size_t)b * CKD * HW;
    dst += (size_t)b * HW * CKD;

    const int c = t >> 2, mb = (t & 3) * 16;
    #pragma unroll
    for (int i = 0; i < 4; ++i) {
      float4 v = *(const float4*)(src + (size_t)c * HW + m0 + mb + i * 4);
      tile[(mb + i*4 + 0) * PSTR + c] = (short)f2bf(v.x);
      tile[(mb + i*4 + 1) * PSTR + c] = (short)f2bf(v.y);
      tile[(mb + i*4 + 2) * PSTR + c] = (short)f2bf(v.z);
      tile[(mb + i*4 + 3) * PSTR + c] = (short)f2bf(v.w);
    }
    __syncthreads();
    const int mr = t >> 2, cp = (t & 3) * 16;
    intx4 r0 = *(const intx4*)(tile + mr * PSTR + cp);
    intx4 r1 = *(const intx4*)(tile + mr * PSTR + cp + 8);
    *(intx4*)(dst + (size_t)(m0 + mr) * CKD + cp)     = r0;
    *(intx4*)(dst + (size_t)(m0 + mr) * CKD + cp + 8) = r1;
  } else {
    // mv elementwise cvt: 8 floats / thread
    const size_t i = ((size_t)(bid - 1024) * 256 + t) * 8;
    float4 v0 = *(const float4*)(Mv + i);
    float4 v1 = *(const float4*)(Mv + i + 4);
    intx4 r;
    r[0] = (int)pack2(v0.x, v0.y);
    r[1] = (int)pack2(v0.z, v0.w);
    r[2] = (int)pack2(v1.x, v1.y);
    r[3] = (int)pack2(v1.z, v1.w);
    *(intx4*)(mvB + i) = r;
  }
}

template<bool BF>
__global__ __launch_bounds__(512, 4) void attn_main(
    const void* __restrict__ MkP, const void* __restrict__ QkP,
    const void* __restrict__ MvP, float* __restrict__ Out)
{
  __shared__ alignas(16) short Pt[2][BQ * PSTR];   // 18432 B
  __shared__ float lsum[BQ];

  const int bx   = blockIdx.x;
  const int b    = bx & 7;            // batch -> XCD affinity
  const int q0   = (bx >> 3) * BQ;
  const int tid  = threadIdx.x;
  const int w    = tid >> 6;
  const int lane = tid & 63;
  const int quad = lane >> 4;
  const int col  = lane & 15;
  const int qhat = w >> 1;            // wave's GEMM1 q-tile
  const int mb   = (w & 1) * 2;       // wave's GEMM1 m-tile pair

  float* out = Out + (size_t)b * CVD * HW;

  if (tid < BQ) lsum[tid] = 0.0f;

  // qk B-fragments, fixed per block: B[k=c][n=q]
  short8 bq[2];
  {
    const int q = q0 + qhat * 16 + col;
    if constexpr (BF) {
      const unsigned short* qkT = (const unsigned short*)QkP + (size_t)b * HW * CKD;
      bq[0] = ld_bf16x8(qkT + (size_t)q * CKD + quad * 8);
      bq[1] = ld_bf16x8(qkT + (size_t)q * CKD + 32 + quad * 8);
    } else {
      const float* qk = (const float*)QkP + (size_t)b * CKD * HW;
      bq[0] = cvt_f32x8_strided(qk + (size_t)(quad * 8) * HW + q);
      bq[1] = cvt_f32x8_strided(qk + (size_t)(32 + quad * 8) * HW + q);
    }
  }

  floatx4 acc[4][4];
  #pragma unroll
  for (int i = 0; i < 4; ++i)
    #pragma unroll
    for (int j = 0; j < 4; ++j) acc[i][j] = (floatx4)0.0f;

  float lacc = 0.0f;
  const float SC = 0.18033688011112042f;   // (1/8) * log2(e)

  __syncthreads();

  for (int it = 0; it < NIT; ++it) {
    const int m0 = it * 64;
    short* Pb = &Pt[it & 1][0];

    // ---- GEMM1: wave computes 2 S-tiles (m-tiles mb,mb+1) x (q-tile qhat)
    #pragma unroll
    for (int t2 = 0; t2 < 2; ++t2) {
      const int mh = mb + t2;
      const int m  = m0 + mh * 16 + col;
      short8 a0, a1;
      if constexpr (BF) {
        const unsigned short* mkT = (const unsigned short*)MkP + (size_t)b * HW * CKD;
        a0 = ld_bf16x8(mkT + (size_t)m * CKD + quad * 8);
        a1 = ld_bf16x8(mkT + (size_t)m * CKD + 32 + quad * 8);
      } else {
        const float* mk = (const float*)MkP + (size_t)b * CKD * HW;
        a0 = cvt_f32x8_strided(mk + (size_t)(quad * 8) * HW + m);
        a1 = cvt_f32x8_strided(mk + (size_t)(32 + quad * 8) * HW + m);
      }
      floatx4 s = (floatx4)0.0f;
      s = __builtin_amdgcn_mfma_f32_16x16x32_bf16(a0, bq[0], s, 0, 0, 0);
      s = __builtin_amdgcn_mfma_f32_16x16x32_bf16(a1, bq[1], s, 0, 0, 0);
      // C layout: q = col, m_local = quad*4 + r
      const float p0 = exp2f(s[0] * SC);
      const float p1 = exp2f(s[1] * SC);
      const float p2 = exp2f(s[2] * SC);
      const float p3 = exp2f(s[3] * SC);
      lacc += (p0 + p1) + (p2 + p3);
      intx2 pv;
      pv[0] = (int)pack2(p0, p1);
      pv[1] = (int)pack2(p2, p3);
      *(intx2*)(Pb + (qhat * 16 + col) * PSTR + mh * 16 + quad * 4) = pv;
    }
    __syncthreads();   // single barrier/iter; P double-buffered

    // ---- GEMM2: O[cv][q] += mv[cv][m] * P[m][q]; wave owns cv [w*64, w*64+64)
    short8 av[4][2];
    #pragma unroll
    for (int ch = 0; ch < 4; ++ch) {
      const int cv = w * 64 + ch * 16 + col;
      if constexpr (BF) {
        const unsigned short* mv = (const unsigned short*)MvP + (size_t)b * CVD * HW;
        av[ch][0] = ld_bf16x8(mv + (size_t)cv * HW + m0 + quad * 8);
        av[ch][1] = ld_bf16x8(mv + (size_t)cv * HW + m0 + 32 + quad * 8);
      } else {
        const float* mv = (const float*)MvP + (size_t)b * CVD * HW;
        av[ch][0] = cvt_f32x8(mv + (size_t)cv * HW + m0 + quad * 8);
        av[ch][1] = cvt_f32x8(mv + (size_t)cv * HW + m0 + 32 + quad * 8);
      }
    }
    #pragma unroll
    for (int qh = 0; qh < 4; ++qh) {
      union { intx4 i; short8 s; } u0, u1;
      u0.i = *(const intx4*)(Pb + (qh * 16 + col) * PSTR + quad * 8);
      u1.i = *(const intx4*)(Pb + (qh * 16 + col) * PSTR + 32 + quad * 8);
      #pragma unroll
      for (int ch = 0; ch < 4; ++ch) {
        acc[ch][qh] = __builtin_amdgcn_mfma_f32_16x16x32_bf16(av[ch][0], u0.s, acc[ch][qh], 0, 0, 0);
        acc[ch][qh] = __builtin_amdgcn_mfma_f32_16x16x32_bf16(av[ch][1], u1.s, acc[ch][qh], 0, 0, 0);
      }
    }
  }

  atomicAdd(&lsum[qhat * 16 + col], lacc);
  __syncthreads();

  float rl[4];
  #pragma unroll
  for (int qh = 0; qh < 4; ++qh) rl[qh] = 1.0f / lsum[qh * 16 + col];

  #pragma unroll
  for (int ch = 0; ch < 4; ++ch) {
    #pragma unroll
    for (int r = 0; r < 4; ++r) {
      const int cv = w * 64 + ch * 16 + quad * 4 + r;
      float* orow = out + (size_t)cv * HW + q0 + col;
      #pragma unroll
      for (int qh = 0; qh < 4; ++qh)
        orow[qh * 16] = acc[ch][qh][r] * rl[qh];
    }
  }
}

extern "C" void kernel_launch(void* const* d_in, const int* in_sizes, int n_in,
                              void* d_out, int out_size, void* d_ws, size_t ws_size,
                              hipStream_t stream) {
  const float* Mk = (const float*)d_in[0];
  const float* Qk = (const float*)d_in[1];
  const float* Mv = (const float*)d_in[2];
  float* Out = (float*)d_out;
  (void)in_sizes; (void)n_in; (void)out_size;

  const size_t NMK = (size_t)NBATCH * CKD * HW;   // 2,097,152
  const size_t NMV = (size_t)NBATCH * CVD * HW;   // 16,777,216
  const size_t need = (2 * NMK + NMV) * 2;        // 41,943,040 B

  if (ws_size >= need) {
    unsigned short* mkT = (unsigned short*)d_ws;
    unsigned short* qkT = mkT + NMK;
    unsigned short* mvB = qkT + NMK;
    const int prep_blocks = 1024 + (int)(NMV / (256 * 8));   // 1024 + 8192
    prep<<<prep_blocks, 256, 0, stream>>>(Mk, Qk, Mv, mkT, qkT, mvB);
    attn_main<true><<<NBATCH * (HW / BQ), 512, 0, stream>>>(mkT, qkT, mvB, Out);
  } else {
    attn_main<false><<<NBATCH * (HW / BQ), 512, 0, stream>>>(Mk, Qk, Mv, Out);
  }
}

// Round 4
// 412.838 us; speedup vs baseline: 1.2310x; 1.2310x over previous
//
#include <hip/hip_runtime.h>

#define HW     4096
#define CKD    64
#define CVD    512
#define NBATCH 8
#define BQ     128
#define BM     128
#define NIT    32      // HW / BM
#define PST    136     // P row stride in shorts (BM+8): 272 B, 16B-aligned
#define TST    72      // prep transpose tile stride (shorts)

typedef __attribute__((ext_vector_type(8))) short  short8;
typedef __attribute__((ext_vector_type(4))) float  floatx4;
typedef __attribute__((ext_vector_type(4))) int    intx4;
typedef __attribute__((ext_vector_type(2))) int    intx2;

#if __has_builtin(__builtin_amdgcn_exp2f)
#define EXP2F(x) __builtin_amdgcn_exp2f(x)
#else
#define EXP2F(x) exp2f(x)
#endif

static __device__ __forceinline__ unsigned short f2bf(float f) {
  unsigned u = __float_as_uint(f);
  u = (u + 0x7fffu + ((u >> 16) & 1u)) >> 16;   // RTNE
  return (unsigned short)u;
}
static __device__ __forceinline__ unsigned pack_rtne(float a, float b) {
  return (unsigned)f2bf(a) | ((unsigned)f2bf(b) << 16);
}
// round-half-up pack: 3 ops, differs from RTNE only on exact ties
static __device__ __forceinline__ unsigned pack_fast(float a, float b) {
  unsigned ua = __float_as_uint(a) + 0x8000u;
  unsigned ub = __float_as_uint(b) + 0x8000u;
  return (ua >> 16) | (ub & 0xffff0000u);
}
static __device__ __forceinline__ short8 ld_bf16x8(const unsigned short* p) {
  union { intx4 i; short8 s; } u;
  u.i = *(const intx4*)p;
  return u.s;
}
static __device__ __forceinline__ short8 cvt_f32x8(const float* p) {
  short8 f;
  #pragma unroll
  for (int j = 0; j < 8; ++j) f[j] = (short)f2bf(p[j]);
  return f;
}
static __device__ __forceinline__ short8 cvt_f32x8_strided(const float* p) {
  short8 f;
  #pragma unroll
  for (int j = 0; j < 8; ++j) f[j] = (short)f2bf(p[(size_t)j * HW]);
  return f;
}

// ---- prep: Mk/Qk f32 [b][c][m] -> bf16 [b][m][c]; Mv f32 -> bf16 ----
__global__ __launch_bounds__(256) void prep(
    const float* __restrict__ Mk, const float* __restrict__ Qk,
    const float* __restrict__ Mv,
    unsigned short* __restrict__ mkT, unsigned short* __restrict__ qkT,
    unsigned short* __restrict__ mvB)
{
  const int bid = blockIdx.x, t = threadIdx.x;
  if (bid < 1024) {
    __shared__ alignas(16) short tile[64 * TST];
    const float* src = (bid >> 9) ? Qk : Mk;
    unsigned short* dst = (bid >> 9) ? qkT : mkT;
    const int b  = (bid >> 6) & 7;
    const int m0 = (bid & 63) * 64;
    src += (size_t)b * CKD * HW;
    dst += (size_t)b * HW * CKD;
    #pragma unroll
    for (int p = 0; p < 4; ++p) {
      const int idx = p * 256 + t;
      const int c = idx >> 4, mc = idx & 15;      // row c, 4-float chunk mc
      float4 v = *(const float4*)(src + (size_t)c * HW + m0 + mc * 4);
      tile[(mc*4 + 0) * TST + c] = (short)f2bf(v.x);
      tile[(mc*4 + 1) * TST + c] = (short)f2bf(v.y);
      tile[(mc*4 + 2) * TST + c] = (short)f2bf(v.z);
      tile[(mc*4 + 3) * TST + c] = (short)f2bf(v.w);
    }
    __syncthreads();
    #pragma unroll
    for (int p = 0; p < 2; ++p) {
      const int idx = p * 256 + t;
      const int m = idx >> 3, cc = idx & 7;
      intx4 r = *(const intx4*)(tile + m * TST + cc * 8);
      __builtin_nontemporal_store(r, (intx4*)(dst + (size_t)(m0 + m) * CKD + cc * 8));
    }
  } else {
    const size_t base = ((size_t)(bid - 1024) * 256 + t) * 16;
    float4 v0 = *(const float4*)(Mv + base);
    float4 v1 = *(const float4*)(Mv + base + 4);
    float4 v2 = *(const float4*)(Mv + base + 8);
    float4 v3 = *(const float4*)(Mv + base + 12);
    intx4 r0, r1;
    r0[0] = (int)pack_rtne(v0.x, v0.y); r0[1] = (int)pack_rtne(v0.z, v0.w);
    r0[2] = (int)pack_rtne(v1.x, v1.y); r0[3] = (int)pack_rtne(v1.z, v1.w);
    r1[0] = (int)pack_rtne(v2.x, v2.y); r1[1] = (int)pack_rtne(v2.z, v2.w);
    r1[2] = (int)pack_rtne(v3.x, v3.y); r1[3] = (int)pack_rtne(v3.z, v3.w);
    __builtin_nontemporal_store(r0, (intx4*)(mvB + base));
    __builtin_nontemporal_store(r1, (intx4*)(mvB + base + 8));
  }
}

// GEMM1 phase for one 128m x 128q S-tile stripe: wave w owns q-tile w, m-tiles 0..7
template<bool BF>
static __device__ __forceinline__ void gemm1_phase(
    const void* mkP, short* Pb, int m0, int w, int col, int quad,
    const short8& bq0, const short8& bq1, float& lacc)
{
  short8 a0[4], a1[4], c0[4], c1[4];
  if constexpr (BF) {
    const unsigned short* mkT = (const unsigned short*)mkP;
    #pragma unroll
    for (int mh = 0; mh < 4; ++mh) {
      const unsigned short* p = mkT + (size_t)(m0 + mh*16 + col) * CKD + quad * 8;
      a0[mh] = ld_bf16x8(p);
      a1[mh] = ld_bf16x8(p + 32);
    }
    #pragma unroll
    for (int mh = 0; mh < 4; ++mh) {
      const unsigned short* p = mkT + (size_t)(m0 + (mh+4)*16 + col) * CKD + quad * 8;
      c0[mh] = ld_bf16x8(p);
      c1[mh] = ld_bf16x8(p + 32);
    }
  } else {
    const float* mk = (const float*)mkP;
    #pragma unroll
    for (int mh = 0; mh < 4; ++mh) {
      a0[mh] = cvt_f32x8_strided(mk + (size_t)(quad*8) * HW + m0 + mh*16 + col);
      a1[mh] = cvt_f32x8_strided(mk + (size_t)(32 + quad*8) * HW + m0 + mh*16 + col);
      c0[mh] = cvt_f32x8_strided(mk + (size_t)(quad*8) * HW + m0 + (mh+4)*16 + col);
      c1[mh] = cvt_f32x8_strided(mk + (size_t)(32 + quad*8) * HW + m0 + (mh+4)*16 + col);
    }
  }
  const float SC = 0.18033688011112042f;   // (1/8) * log2(e)
  #pragma unroll
  for (int half = 0; half < 2; ++half) {
    #pragma unroll
    for (int mh = 0; mh < 4; ++mh) {
      floatx4 s = (floatx4)0.0f;
      if (half == 0) {
        s = __builtin_amdgcn_mfma_f32_16x16x32_bf16(a0[mh], bq0, s, 0, 0, 0);
        s = __builtin_amdgcn_mfma_f32_16x16x32_bf16(a1[mh], bq1, s, 0, 0, 0);
      } else {
        s = __builtin_amdgcn_mfma_f32_16x16x32_bf16(c0[mh], bq0, s, 0, 0, 0);
        s = __builtin_amdgcn_mfma_f32_16x16x32_bf16(c1[mh], bq1, s, 0, 0, 0);
      }
      const float p0 = EXP2F(s[0] * SC);
      const float p1 = EXP2F(s[1] * SC);
      const float p2 = EXP2F(s[2] * SC);
      const float p3 = EXP2F(s[3] * SC);
      lacc += (p0 + p1) + (p2 + p3);
      intx2 pv;
      pv[0] = (int)pack_fast(p0, p1);
      pv[1] = (int)pack_fast(p2, p3);
      const int mloc = (half * 4 + mh) * 16 + quad * 4;
      *(intx2*)(Pb + (w*16 + col) * PST + mloc) = pv;
    }
  }
}

template<bool BF>
__global__ __launch_bounds__(512, 2) void attn_main(
    const void* __restrict__ MkP, const void* __restrict__ QkP,
    const void* __restrict__ MvP, float* __restrict__ Out)
{
  __shared__ alignas(16) short Pt[2][BQ * PST];   // 69632 B
  __shared__ float lsum[BQ];

  const int bx   = blockIdx.x;
  const int b    = bx & 7;            // batch -> XCD affinity
  const int q0   = (bx >> 3) * BQ;
  const int tid  = threadIdx.x;
  const int w    = tid >> 6;
  const int lane = tid & 63;
  const int quad = lane >> 4;
  const int col  = lane & 15;

  const size_t esz = BF ? 2 : 4;
  const char* mkB = (const char*)MkP + (size_t)b * CKD * HW * esz;
  const char* mvB = (const char*)MvP + (size_t)b * CVD * HW * esz;
  float* out = Out + (size_t)b * CVD * HW;

  if (tid < BQ) lsum[tid] = 0.0f;

  // qk B-fragments (fixed per block): wave w owns q-tile w
  short8 bq0, bq1;
  {
    const int q = q0 + w * 16 + col;
    if constexpr (BF) {
      const unsigned short* qkT = (const unsigned short*)QkP + (size_t)b * HW * CKD;
      bq0 = ld_bf16x8(qkT + (size_t)q * CKD + quad * 8);
      bq1 = ld_bf16x8(qkT + (size_t)q * CKD + 32 + quad * 8);
    } else {
      const float* qk = (const float*)QkP + (size_t)b * CKD * HW;
      bq0 = cvt_f32x8_strided(qk + (size_t)(quad * 8) * HW + q);
      bq1 = cvt_f32x8_strided(qk + (size_t)(32 + quad * 8) * HW + q);
    }
  }

  floatx4 acc[4][8];
  #pragma unroll
  for (int i = 0; i < 4; ++i)
    #pragma unroll
    for (int j = 0; j < 8; ++j) acc[i][j] = (floatx4)0.0f;
  float lacc = 0.0f;

  // GEMM1 for it=0 into Pt[0]
  gemm1_phase<BF>(mkB, &Pt[0][0], 0, w, col, quad, bq0, bq1, lacc);

  for (int it = 0; it < NIT; ++it) {
    __syncthreads();                 // P(it) ready; Pt[(it+1)&1] free
    const short* Pb = &Pt[it & 1][0];
    const int m0 = it * BM;

    // ---- GEMM2: O[cv][q] += mv[cv][m] * P[m][q]; wave owns cv [w*64, w*64+64)
    short8 av[2][4];
    #pragma unroll
    for (int ch = 0; ch < 4; ++ch) {
      if constexpr (BF)
        av[0][ch] = ld_bf16x8((const unsigned short*)mvB +
                              (size_t)(w*64 + ch*16 + col) * HW + m0 + quad * 8);
      else
        av[0][ch] = cvt_f32x8((const float*)mvB +
                              (size_t)(w*64 + ch*16 + col) * HW + m0 + quad * 8);
    }
    #pragma unroll
    for (int ks = 0; ks < 4; ++ks) {
      if (ks < 3) {
        #pragma unroll
        for (int ch = 0; ch < 4; ++ch) {
          if constexpr (BF)
            av[(ks+1)&1][ch] = ld_bf16x8((const unsigned short*)mvB +
                (size_t)(w*64 + ch*16 + col) * HW + m0 + (ks+1)*32 + quad * 8);
          else
            av[(ks+1)&1][ch] = cvt_f32x8((const float*)mvB +
                (size_t)(w*64 + ch*16 + col) * HW + m0 + (ks+1)*32 + quad * 8);
        }
      }
      #pragma unroll
      for (int qh = 0; qh < 8; ++qh) {
        union { intx4 i; short8 s; } u;
        u.i = *(const intx4*)(Pb + (qh*16 + col) * PST + ks*32 + quad * 8);
        #pragma unroll
        for (int ch = 0; ch < 4; ++ch)
          acc[ch][qh] = __builtin_amdgcn_mfma_f32_16x16x32_bf16(av[ks&1][ch], u.s,
                                                                acc[ch][qh], 0, 0, 0);
      }
    }

    // ---- GEMM1 for it+1 into the other buffer
    if (it + 1 < NIT)
      gemm1_phase<BF>(mkB, &Pt[(it+1) & 1][0], m0 + BM, w, col, quad, bq0, bq1, lacc);
  }

  atomicAdd(&lsum[w*16 + col], lacc);
  __syncthreads();

  float rl[8];
  #pragma unroll
  for (int qh = 0; qh < 8; ++qh) rl[qh] = 1.0f / lsum[qh*16 + col];

  #pragma unroll
  for (int ch = 0; ch < 4; ++ch) {
    #pragma unroll
    for (int r = 0; r < 4; ++r) {
      const int cv = w*64 + ch*16 + quad*4 + r;
      float* orow = out + (size_t)cv * HW + q0 + col;
      #pragma unroll
      for (int qh = 0; qh < 8; ++qh)
        __builtin_nontemporal_store(acc[ch][qh][r] * rl[qh], orow + qh*16);
    }
  }
}

extern "C" void kernel_launch(void* const* d_in, const int* in_sizes, int n_in,
                              void* d_out, int out_size, void* d_ws, size_t ws_size,
                              hipStream_t stream) {
  const float* Mk = (const float*)d_in[0];
  const float* Qk = (const float*)d_in[1];
  const float* Mv = (const float*)d_in[2];
  float* Out = (float*)d_out;
  (void)in_sizes; (void)n_in; (void)out_size;

  const size_t NMK = (size_t)NBATCH * CKD * HW;   // 2,097,152
  const size_t NMV = (size_t)NBATCH * CVD * HW;   // 16,777,216
  const size_t need = (2 * NMK + NMV) * 2;        // 41,943,040 B

  if (ws_size >= need) {
    unsigned short* mkT = (unsigned short*)d_ws;
    unsigned short* qkT = mkT + NMK;
    unsigned short* mvW = qkT + NMK;
    const int prep_blocks = 1024 + (int)(NMV / (256 * 16));   // 1024 + 4096
    prep<<<prep_blocks, 256, 0, stream>>>(Mk, Qk, Mv, mkT, qkT, mvW);
    attn_main<true><<<NBATCH * (HW / BQ), 512, 0, stream>>>(mkT, qkT, mvW, Out);
  } else {
    attn_main<false><<<NBATCH * (HW / BQ), 512, 0, stream>>>(Mk, Qk, Mv, Out);
  }
}